// Round 4
// baseline (120.822 us; speedup 1.0000x reference)
//
#include <hip/hip_runtime.h>

typedef unsigned short u16;
typedef __attribute__((ext_vector_type(8))) short short8;
typedef __attribute__((ext_vector_type(4))) float f32x4;

#define INVT 14.285714285714286f   // 1/0.07
#define KEXP 20.617062471830945f   // INVT * log2(e):  exp((x-1)/T) = exp2(x*KEXP - KEXP)

__device__ __forceinline__ u16 f2bf(float f) {
  union { float f; unsigned u; } v; v.f = f;
  unsigned u = v.u;
  u += 0x7fffu + ((u >> 16) & 1u);  // round-to-nearest-even
  return (u16)(u >> 16);
}
__device__ __forceinline__ float bf2f(u16 h) {
  union { unsigned u; float f; } v; v.u = ((unsigned)h) << 16;
  return v.f;
}
__device__ __forceinline__ void glds16(const u16* g, u16* l) {
  __builtin_amdgcn_global_load_lds((const __attribute__((address_space(1))) void*)g,
                                   (__attribute__((address_space(3))) void*)l,
                                   16, 0, 0);
}

// Kernel 1: normalize rows -> bf16 F; dvec_i = exp((||f̂||²-1)/T); pos_i;
// zero E[2N] and the ticket counter. 512 blocks x 256 (4 waves, 2 row-pairs each).
__global__ __launch_bounds__(256) void norm_kernel(
    const float* __restrict__ f1, const float* __restrict__ f2,
    u16* __restrict__ F, float* __restrict__ dvec, float* __restrict__ pos,
    float* __restrict__ E, int* __restrict__ done, int N) {
  const int b = blockIdx.x, tid = threadIdx.x;
  const int wave = tid >> 6, l = tid & 63;
  int gid = b * 256 + tid;
  if (gid < 2 * N) E[gid] = 0.0f;
  if (gid == 0) *done = 0;
#pragma unroll
  for (int it = 0; it < 2; ++it) {
    int i = b * 8 + wave * 2 + it;
    if (i >= N) break;
    const float* a = f1 + (size_t)i * 128;
    const float* c = f2 + (size_t)i * 128;
    float a0 = a[l], a1 = a[l + 64];
    float b0 = c[l], b1 = c[l + 64];
    float sa = a0 * a0 + a1 * a1;
    float sb = b0 * b0 + b1 * b1;
#pragma unroll
    for (int o = 32; o; o >>= 1) { sa += __shfl_xor(sa, o); sb += __shfl_xor(sb, o); }
    float ia = 1.0f / fmaxf(sqrtf(sa), 1e-12f);
    float ib = 1.0f / fmaxf(sqrtf(sb), 1e-12f);
    u16 ba0 = f2bf(a0 * ia), ba1 = f2bf(a1 * ia);
    u16 bb0 = f2bf(b0 * ib), bb1 = f2bf(b1 * ib);
    u16* Fa = F + (size_t)i * 128;
    u16* Fb = F + (size_t)(i + N) * 128;
    Fa[l] = ba0; Fa[l + 64] = ba1;
    Fb[l] = bb0; Fb[l + 64] = bb1;
    // self/cross dots of the bf16-rounded values (what the MFMA will see)
    float fa0 = bf2f(ba0), fa1 = bf2f(ba1);
    float fb0 = bf2f(bb0), fb1 = bf2f(bb1);
    float s1 = fa0 * fa0 + fa1 * fa1;
    float s2 = fb0 * fb0 + fb1 * fb1;
    float cr = fa0 * fb0 + fa1 * fb1;
#pragma unroll
    for (int o = 32; o; o >>= 1) {
      s1 += __shfl_xor(s1, o); s2 += __shfl_xor(s2, o); cr += __shfl_xor(cr, o);
    }
    if (l == 0) {
      dvec[i]     = exp2f(fmaf(s1, KEXP, -KEXP));
      dvec[i + N] = exp2f(fmaf(s2, KEXP, -KEXP));
      pos[i] = cr;
      pos[i + N] = cr;
    }
  }
}

// Kernel 2: persistent triangular tiles of S = F Fᵀ. Each block handles a
// contiguous run of row-major triangular indices (Bt reused across the run,
// diagonal tiles skip At). exp((s-1)/T) summed into cols + rows -> atomic E.
// Last block (device ticket) computes the loss and writes out.
__global__ __launch_bounds__(256, 2) void gemm_exp_kernel(
    const u16* __restrict__ F, float* __restrict__ E,
    const float* __restrict__ dvec, const float* __restrict__ pos,
    int* __restrict__ done, float* __restrict__ out, int TWO_N, int NT) {
  __shared__ __align__(16) u16 At[128 * 128];  // 32 KB
  __shared__ __align__(16) u16 Bt[128 * 128];  // 32 KB
  __shared__ float colsum[128];
  __shared__ float rowsum[128];
  __shared__ int ticket_s;
  const int b = blockIdx.x, tid = threadIdx.x;
  const int wave = tid >> 6, lane = tid & 63;
  const int G = gridDim.x;

  const int start = (int)(((long)NT * b) / G);
  const int end   = (int)(((long)NT * (b + 1)) / G);
  // decode start -> (bj, bi<=bj)
  int bj = (int)((sqrtf(8.0f * (float)start + 1.0f) - 1.0f) * 0.5f);
  while ((bj + 1) * (bj + 2) / 2 <= start) ++bj;
  while (bj * (bj + 1) / 2 > start) --bj;
  int bi = start - bj * (bj + 1) / 2;
  int cur_bj = -1;
  const int wr = wave >> 1, wc = wave & 1;  // 2x2 waves, each 64x64
  const int q = lane >> 4, m = lane & 15;

  for (int p = start; p < end; ++p) {
    if (tid < 128) { colsum[tid] = 0.0f; rowsum[tid] = 0.0f; }
    const bool diag = (bi == bj);
    // stage (16B/lane DMA; LDS granule (r,c) holds global granule (r, c^(r&7)))
    if (bj != cur_bj) {
      const u16* Bb = F + (size_t)bj * (128 * 128);
#pragma unroll
      for (int t = 0; t < 8; ++t) {
        int chunk = wave * 8 + t;
        int g = chunk * 64 + lane;
        int gg = g ^ ((g >> 4) & 7);
        glds16(Bb + (size_t)gg * 8, &Bt[chunk * 512]);
      }
      cur_bj = bj;
    }
    if (!diag) {
      const u16* Ab = F + (size_t)bi * (128 * 128);
#pragma unroll
      for (int t = 0; t < 8; ++t) {
        int chunk = wave * 8 + t;
        int g = chunk * 64 + lane;
        int gg = g ^ ((g >> 4) & 7);
        glds16(Ab + (size_t)gg * 8, &At[chunk * 512]);
      }
    }
    __syncthreads();  // staging done; also orders colsum zero before epilogue adds

    const u16* asrc = diag ? Bt : At;
    f32x4 acc[4][4];
#pragma unroll
    for (int fr = 0; fr < 4; ++fr)
#pragma unroll
      for (int cf = 0; cf < 4; ++cf) acc[fr][cf] = (f32x4)(0.0f);

#pragma unroll
    for (int ks = 0; ks < 4; ++ks) {
      const int c = ks * 4 + q;  // k-granule (8 bf16 each)
      short8 av[4], bv[4];
#pragma unroll
      for (int fr = 0; fr < 4; ++fr) {
        int rr = wr * 64 + fr * 16 + m;
        av[fr] = *(const short8*)&asrc[rr * 128 + ((c ^ (rr & 7)) * 8)];
      }
#pragma unroll
      for (int cf = 0; cf < 4; ++cf) {
        int rr = wc * 64 + cf * 16 + m;
        bv[cf] = *(const short8*)&Bt[rr * 128 + ((c ^ (rr & 7)) * 8)];
      }
#pragma unroll
      for (int fr = 0; fr < 4; ++fr)
#pragma unroll
        for (int cf = 0; cf < 4; ++cf)
          acc[fr][cf] = __builtin_amdgcn_mfma_f32_16x16x32_bf16(av[fr], bv[cf], acc[fr][cf], 0, 0, 0);
    }

    // Epilogue. C-layout: col = m (+cf*16+wc*64), row = q*4+rg (+fr*16+wr*64).
    float cs[4] = {0.f, 0.f, 0.f, 0.f};
    float v[16];
#pragma unroll
    for (int i = 0; i < 16; ++i) v[i] = 0.f;
#pragma unroll
    for (int cf = 0; cf < 4; ++cf)
#pragma unroll
      for (int fr = 0; fr < 4; ++fr)
#pragma unroll
        for (int rg = 0; rg < 4; ++rg) {
          float e = exp2f(fmaf(acc[fr][cf][rg], KEXP, -KEXP));
          cs[cf] += e;
          v[fr * 4 + rg] += e;
        }
    // column sums: reduce across quads (rows)
#pragma unroll
    for (int cf = 0; cf < 4; ++cf) {
      cs[cf] += __shfl_xor(cs[cf], 16);
      cs[cf] += __shfl_xor(cs[cf], 32);
      if (q == 0) atomicAdd(&colsum[wc * 64 + cf * 16 + m], cs[cf]);
    }
    // row sums (off-diag only): value-halving butterfly over the 16 m-lanes.
    // After steps 8/4/2/1, lane (q,m) holds the full sum for idx==m,
    // i.e. row (m>>2)*16 + q*4 + (m&3). One conflict-free LDS atomic per lane.
    if (!diag) {
      float t16[16];
#pragma unroll
      for (int i = 0; i < 16; ++i) t16[i] = __shfl_xor(v[i], 8);
      bool hi = (m & 8) != 0;
#pragma unroll
      for (int i = 0; i < 8; ++i) v[i] = hi ? (v[i + 8] + t16[i + 8]) : (v[i] + t16[i]);
#pragma unroll
      for (int i = 0; i < 8; ++i) t16[i] = __shfl_xor(v[i], 4);
      hi = (m & 4) != 0;
#pragma unroll
      for (int i = 0; i < 4; ++i) v[i] = hi ? (v[i + 4] + t16[i + 4]) : (v[i] + t16[i]);
#pragma unroll
      for (int i = 0; i < 4; ++i) t16[i] = __shfl_xor(v[i], 2);
      hi = (m & 2) != 0;
#pragma unroll
      for (int i = 0; i < 2; ++i) v[i] = hi ? (v[i + 2] + t16[i + 2]) : (v[i] + t16[i]);
      t16[0] = __shfl_xor(v[0], 1);
      t16[1] = __shfl_xor(v[1], 1);
      v[0] = (m & 1) ? (v[1] + t16[1]) : (v[0] + t16[0]);
      atomicAdd(&rowsum[wr * 64 + (m >> 2) * 16 + q * 4 + (m & 3)], v[0]);
    }
    __syncthreads();  // epilogue adds done; protects At/Bt for next iter too
    if (tid < 128) {
      atomicAdd(&E[bj * 128 + tid], colsum[tid]);
      if (!diag) atomicAdd(&E[bi * 128 + tid], rowsum[tid]);
    }
    ++bi;
    if (bi > bj) { bi = 0; ++bj; }
  }

  // ---- last-block finalize via device ticket ----
  __threadfence();  // make this block's E atomics visible before the ticket
  if (tid == 0) ticket_s = atomicAdd(done, 1);
  __syncthreads();
  if (ticket_s == G - 1) {
    float t = 0.0f;
    for (int i = tid; i < TWO_N; i += 256) {
      float e = atomicAdd(&E[i], 0.0f);  // RMW read: L2-current, skips stale L1
      t += (pos[i] - 1.0f) * INVT - logf(e - dvec[i]);
    }
#pragma unroll
    for (int o = 32; o; o >>= 1) t += __shfl_xor(t, o);
    if (lane == 0) colsum[wave] = t;
    __syncthreads();
    if (tid == 0)
      out[0] = (colsum[0] + colsum[1] + colsum[2] + colsum[3]) * (-1.0f / (float)TWO_N);
  }
}

extern "C" void kernel_launch(void* const* d_in, const int* in_sizes, int n_in,
                              void* d_out, int out_size, void* d_ws, size_t ws_size,
                              hipStream_t stream) {
  const float* f1 = (const float*)d_in[0];
  const float* f2 = (const float*)d_in[1];
  int N = in_sizes[0] / 128;        // 4096
  int TWO_N = 2 * N;                // 8192
  int NB = TWO_N / 128;             // 64
  int NT = NB * (NB + 1) / 2;       // 2080

  char* ws = (char*)d_ws;
  u16*   F    = (u16*)ws;                                  // 2 MB
  float* dvec = (float*)(ws + (size_t)TWO_N * 128 * 2);    // 2N f32
  float* pos  = dvec + TWO_N;                              // 2N f32
  float* E    = pos + TWO_N;                               // 2N f32
  int*   done = (int*)(E + TWO_N);                         // 1 int

  norm_kernel<<<512, 256, 0, stream>>>(f1, f2, F, dvec, pos, E, done, N);
  gemm_exp_kernel<<<512, 256, 0, stream>>>(F, E, dvec, pos, done, (float*)d_out,
                                           TWO_N, NT);
}

// Round 5
// 92.023 us; speedup vs baseline: 1.3130x; 1.3130x over previous
//
#include <hip/hip_runtime.h>

typedef unsigned short u16;
typedef __attribute__((ext_vector_type(8))) short short8;
typedef __attribute__((ext_vector_type(4))) float f32x4;

#define INVT 14.285714285714286f   // 1/0.07
#define KEXP 20.617062471830945f   // INVT*log2(e): exp((x-1)/T) = exp2(x*KEXP - KEXP)

__device__ __forceinline__ u16 f2bf(float f) {
  union { float f; unsigned u; } v; v.f = f;
  unsigned u = v.u;
  u += 0x7fffu + ((u >> 16) & 1u);  // round-to-nearest-even
  return (u16)(u >> 16);
}
__device__ __forceinline__ float bf2f(u16 h) {
  union { unsigned u; float f; } v; v.u = ((unsigned)h) << 16;
  return v.f;
}
__device__ __forceinline__ void glds16(const u16* g, u16* l) {
  __builtin_amdgcn_global_load_lds((const __attribute__((address_space(1))) void*)g,
                                   (__attribute__((address_space(3))) void*)l,
                                   16, 0, 0);
}

// Kernel 1: normalize rows -> bf16 F; dvec_i = exp((||f̂||²-1)/T); pos_i.
// Also zeroes accum/done. 512 blocks x 256 (4 waves x 2 row-pairs).
__global__ __launch_bounds__(256) void norm_kernel(
    const float* __restrict__ f1, const float* __restrict__ f2,
    u16* __restrict__ F, float* __restrict__ dvec, float* __restrict__ pos,
    float* __restrict__ accum, int* __restrict__ done, int N) {
  const int b = blockIdx.x, tid = threadIdx.x;
  const int wave = tid >> 6, l = tid & 63;
  if (b == 0 && tid == 0) { *accum = 0.0f; *done = 0; }
#pragma unroll
  for (int it = 0; it < 2; ++it) {
    int i = b * 8 + wave * 2 + it;
    if (i >= N) break;
    const float* a = f1 + (size_t)i * 128;
    const float* c = f2 + (size_t)i * 128;
    float a0 = a[l], a1 = a[l + 64];
    float b0 = c[l], b1 = c[l + 64];
    float sa = a0 * a0 + a1 * a1;
    float sb = b0 * b0 + b1 * b1;
#pragma unroll
    for (int o = 32; o; o >>= 1) { sa += __shfl_xor(sa, o); sb += __shfl_xor(sb, o); }
    float ia = 1.0f / fmaxf(sqrtf(sa), 1e-12f);
    float ib = 1.0f / fmaxf(sqrtf(sb), 1e-12f);
    u16 ba0 = f2bf(a0 * ia), ba1 = f2bf(a1 * ia);
    u16 bb0 = f2bf(b0 * ib), bb1 = f2bf(b1 * ib);
    u16* Fa = F + (size_t)i * 128;
    u16* Fb = F + (size_t)(i + N) * 128;
    Fa[l] = ba0; Fa[l + 64] = ba1;
    Fb[l] = bb0; Fb[l + 64] = bb1;
    // self/cross dots of the bf16-rounded values (what the MFMA will see)
    float fa0 = bf2f(ba0), fa1 = bf2f(ba1);
    float fb0 = bf2f(bb0), fb1 = bf2f(bb1);
    float s1 = fa0 * fa0 + fa1 * fa1;
    float s2 = fb0 * fb0 + fb1 * fb1;
    float cr = fa0 * fb0 + fa1 * fb1;
#pragma unroll
    for (int o = 32; o; o >>= 1) {
      s1 += __shfl_xor(s1, o); s2 += __shfl_xor(s2, o); cr += __shfl_xor(cr, o);
    }
    if (l == 0) {
      dvec[i]     = exp2f(fmaf(s1, KEXP, -KEXP));
      dvec[i + N] = exp2f(fmaf(s2, KEXP, -KEXP));
      pos[i] = cr;
      pos[i + N] = cr;
    }
  }
}

// Kernel 2: one 128x128 triangular tile (bi<=bj) of S = F Fᵀ per block.
// exp((s-1)/T), tile column-sums and (off-diag) row-sums -> PURE STORES into
// P[other][j]: P[bi][bj*128+c] = colsum, P[bj][bi*128+r] = rowsum.
// Each (other,j) cell is written exactly once -> no atomics anywhere.
__global__ __launch_bounds__(256, 2) void gemm_exp_kernel(
    const u16* __restrict__ F, float* __restrict__ P, int TWO_N) {
  __shared__ __align__(16) u16 At[128 * 128];  // 32 KB
  __shared__ __align__(16) u16 Bt[128 * 128];  // 32 KB
  __shared__ float colsum[128];
  __shared__ float rowsum[128];
  const int tid = threadIdx.x;
  const int wave = tid >> 6, lane = tid & 63;
  // triangular decode: p -> (bj, bi<=bj)
  int p = blockIdx.x;
  int bj = (int)((sqrtf(8.0f * (float)p + 1.0f) - 1.0f) * 0.5f);
  while ((bj + 1) * (bj + 2) / 2 <= p) ++bj;
  while (bj * (bj + 1) / 2 > p) --bj;
  const int bi = p - bj * (bj + 1) / 2;
  const bool diag = (bi == bj);

  if (tid < 128) { colsum[tid] = 0.0f; rowsum[tid] = 0.0f; }
  // stage (16B/lane DMA; LDS granule (r,c) holds global granule (r, c^(r&7)))
  {
    const u16* Bb = F + (size_t)bj * (128 * 128);
#pragma unroll
    for (int t = 0; t < 8; ++t) {
      int chunk = wave * 8 + t;
      int g = chunk * 64 + lane;
      int gg = g ^ ((g >> 4) & 7);
      glds16(Bb + (size_t)gg * 8, &Bt[chunk * 512]);
    }
  }
  if (!diag) {
    const u16* Ab = F + (size_t)bi * (128 * 128);
#pragma unroll
    for (int t = 0; t < 8; ++t) {
      int chunk = wave * 8 + t;
      int g = chunk * 64 + lane;
      int gg = g ^ ((g >> 4) & 7);
      glds16(Ab + (size_t)gg * 8, &At[chunk * 512]);
    }
  }
  __syncthreads();

  const int wr = wave >> 1, wc = wave & 1;  // 2x2 waves, each 64x64
  const int q = lane >> 4, m = lane & 15;
  const u16* asrc = diag ? Bt : At;
  f32x4 acc[4][4];
#pragma unroll
  for (int fr = 0; fr < 4; ++fr)
#pragma unroll
    for (int cf = 0; cf < 4; ++cf) acc[fr][cf] = (f32x4)(0.0f);

#pragma unroll
  for (int ks = 0; ks < 4; ++ks) {
    const int c = ks * 4 + q;  // k-granule (8 bf16 each)
    short8 av[4], bv[4];
#pragma unroll
    for (int fr = 0; fr < 4; ++fr) {
      int rr = wr * 64 + fr * 16 + m;
      av[fr] = *(const short8*)&asrc[rr * 128 + ((c ^ (rr & 7)) * 8)];
    }
#pragma unroll
    for (int cf = 0; cf < 4; ++cf) {
      int rr = wc * 64 + cf * 16 + m;
      bv[cf] = *(const short8*)&Bt[rr * 128 + ((c ^ (rr & 7)) * 8)];
    }
#pragma unroll
    for (int fr = 0; fr < 4; ++fr)
#pragma unroll
      for (int cf = 0; cf < 4; ++cf)
        acc[fr][cf] = __builtin_amdgcn_mfma_f32_16x16x32_bf16(av[fr], bv[cf], acc[fr][cf], 0, 0, 0);
  }

  // Epilogue. C-layout: col = m (+cf*16+wc*64), row = q*4+rg (+fr*16+wr*64).
  float cs[4] = {0.f, 0.f, 0.f, 0.f};
  float v[16];
#pragma unroll
  for (int i = 0; i < 16; ++i) v[i] = 0.f;
#pragma unroll
  for (int cf = 0; cf < 4; ++cf)
#pragma unroll
    for (int fr = 0; fr < 4; ++fr)
#pragma unroll
      for (int rg = 0; rg < 4; ++rg) {
        float e = exp2f(fmaf(acc[fr][cf][rg], KEXP, -KEXP));
        cs[cf] += e;
        v[fr * 4 + rg] += e;
      }
  // column sums: reduce across quads (rows)
#pragma unroll
  for (int cf = 0; cf < 4; ++cf) {
    cs[cf] += __shfl_xor(cs[cf], 16);
    cs[cf] += __shfl_xor(cs[cf], 32);
    if (q == 0) atomicAdd(&colsum[wc * 64 + cf * 16 + m], cs[cf]);
  }
  // row sums (off-diag only): value-halving butterfly over the 16 m-lanes.
  // After steps 8/4/2/1 lane (q,m) holds the full sum for idx==m,
  // i.e. row (m>>2)*16 + q*4 + (m&3). One conflict-free LDS atomic per lane.
  if (!diag) {
    float t16[16];
#pragma unroll
    for (int i = 0; i < 16; ++i) t16[i] = __shfl_xor(v[i], 8);
    bool hi = (m & 8) != 0;
#pragma unroll
    for (int i = 0; i < 8; ++i) v[i] = hi ? (v[i + 8] + t16[i + 8]) : (v[i] + t16[i]);
#pragma unroll
    for (int i = 0; i < 8; ++i) t16[i] = __shfl_xor(v[i], 4);
    hi = (m & 4) != 0;
#pragma unroll
    for (int i = 0; i < 4; ++i) v[i] = hi ? (v[i + 4] + t16[i + 4]) : (v[i] + t16[i]);
#pragma unroll
    for (int i = 0; i < 4; ++i) t16[i] = __shfl_xor(v[i], 2);
    hi = (m & 2) != 0;
#pragma unroll
    for (int i = 0; i < 2; ++i) v[i] = hi ? (v[i + 2] + t16[i + 2]) : (v[i] + t16[i]);
    t16[0] = __shfl_xor(v[0], 1);
    t16[1] = __shfl_xor(v[1], 1);
    v[0] = (m & 1) ? (v[1] + t16[1]) : (v[0] + t16[0]);
    atomicAdd(&rowsum[wr * 64 + (m >> 2) * 16 + q * 4 + (m & 3)], v[0]);
  }
  __syncthreads();
  if (tid < 128) {
    P[(size_t)bi * TWO_N + bj * 128 + tid] = colsum[tid];
    if (!diag) P[(size_t)bj * TWO_N + bi * 128 + tid] = rowsum[tid];
  }
}

// Kernel 3: E_j = sum_o P[o][j] (coalesced, L2-hot); term_j; block partial ->
// one accum atomic per block; ticket-last block writes out (single RMW).
__global__ __launch_bounds__(256) void reduce_kernel(
    const float* __restrict__ P, const float* __restrict__ dvec,
    const float* __restrict__ pos, float* __restrict__ accum,
    int* __restrict__ done, float* __restrict__ out, int TWO_N, int NB) {
  __shared__ float wpart[4];
  __shared__ int ticket_s;
  const int tid = threadIdx.x;
  const int wave = tid >> 6, lane = tid & 63;
  const int j = blockIdx.x * 256 + tid;
  float e = 0.0f;
#pragma unroll 8
  for (int o = 0; o < NB; ++o) e += P[(size_t)o * TWO_N + j];
  float term = (pos[j] - 1.0f) * INVT - logf(e - dvec[j]);
#pragma unroll
  for (int o = 32; o; o >>= 1) term += __shfl_xor(term, o);
  if (lane == 0) wpart[wave] = term;
  __syncthreads();
  if (tid == 0) {
    atomicAdd(accum, wpart[0] + wpart[1] + wpart[2] + wpart[3]);
    __threadfence();
    ticket_s = atomicAdd(done, 1);
    if (ticket_s == gridDim.x - 1) {
      float tot = atomicAdd(accum, 0.0f);  // device-scope RMW: sees all adds
      out[0] = tot * (-1.0f / (float)TWO_N);
    }
  }
}

extern "C" void kernel_launch(void* const* d_in, const int* in_sizes, int n_in,
                              void* d_out, int out_size, void* d_ws, size_t ws_size,
                              hipStream_t stream) {
  const float* f1 = (const float*)d_in[0];
  const float* f2 = (const float*)d_in[1];
  int N = in_sizes[0] / 128;        // 4096
  int TWO_N = 2 * N;                // 8192
  int NB = TWO_N / 128;             // 64
  int NT = NB * (NB + 1) / 2;       // 2080

  char* ws = (char*)d_ws;
  u16*   F     = (u16*)ws;                                  // 2 MB
  float* dvec  = (float*)(ws + (size_t)TWO_N * 128 * 2);    // 2N f32
  float* pos   = dvec + TWO_N;                              // 2N f32
  float* P     = pos + TWO_N;                               // NB*2N f32 = 2 MB
  float* accum = P + (size_t)NB * TWO_N;                    // 1 f32
  int*   done  = (int*)(accum + 1);                         // 1 int

  norm_kernel<<<512, 256, 0, stream>>>(f1, f2, F, dvec, pos, accum, done, N);
  gemm_exp_kernel<<<NT, 256, 0, stream>>>(F, P, TWO_N);
  reduce_kernel<<<TWO_N / 256, 256, 0, stream>>>(P, dvec, pos, accum, done,
                                                 (float*)d_out, TWO_N, NB);
}